// Round 4
// baseline (257.475 us; speedup 1.0000x reference)
//
#include <hip/hip_runtime.h>

#define EDIM     512
#define NTOK     (512 * 128)   // B*S = 65536
#define NTHREADS 256
#define TPB_A    32            // tokens per block, phase A (8 lanes/token)
#define NBLK_A   (NTOK / TPB_A) // 2048 blocks -> 8/CU
#define TPB_B    32            // tokens per block, phase B
#define NBLK_B   (NTOK / TPB_B) // 2048 blocks -> 8/CU

typedef unsigned short u16;
typedef unsigned int   u32;
typedef float v4f __attribute__((ext_vector_type(4)));
typedef u16   v4h __attribute__((ext_vector_type(4)));

__device__ __forceinline__ float bf2f(u16 u) { return __uint_as_float(((u32)u) << 16); }

__device__ __forceinline__ u32 f2bfbits(float f) {
    // round-to-nearest-even f32 -> bf16
    u32 b = __float_as_uint(f);
    return (b + 0x7fffu + ((b >> 16) & 1u)) >> 16;
}

template<bool BF16>
__device__ __forceinline__ float ld1(const void* p, int off) {
    if constexpr (BF16) return bf2f(((const u16*)p)[off]);
    else                return ((const float*)p)[off];
}

// ---- 3-way container detection, per-block (reads first 2 KB of x) ----------
// true bf16 container : low u16 of word is valid N(0,1)-scale bf16 -> v~512
// true f32 container  : low u16 random mantissa -> v~19%, z~0
// f32 holding bf16-rounded values: low u16 == 0 -> z~512
__device__ __forceinline__ bool detect_block(const u32* xw, int tid, int* s_zc, int* s_vc)
{
    if (tid == 0) { *s_zc = 0; *s_vc = 0; }
    __syncthreads();
    int z = 0, v = 0;
    #pragma unroll
    for (int i = 0; i < 2; ++i) {
        const u32 w = xw[tid + 256 * i];
        if ((w & 0xFFFFu) == 0u) z++;
        const u32 e = (w >> 7) & 0xFFu;
        if (e != 0u && e >= 96u && e <= 143u) v++;
    }
    if (z) atomicAdd(s_zc, z);
    if (v) atomicAdd(s_vc, v);
    __syncthreads();
    return (*s_zc < 384 && *s_vc >= 384);
}

// ---- shared circuit: qin[4] -> qout[4] (verbatim from verified kernel) -----
__device__ __forceinline__ void circuit4(const float qin[4], const float* s_trig, float qout[4])
{
    float cw[4], sw[4];
    #pragma unroll
    for (int w = 0; w < 4; ++w) sincosf(0.5f * qin[w], &sw[w], &cw[w]);

    float re[16], im[16];
    re[0] = 1.f; im[0] = 0.f;
    #pragma unroll
    for (int w = 0; w < 4; ++w) {
        #pragma unroll
        for (int j = (1 << w) - 1; j >= 0; --j) {
            const float r0 = re[j], i0 = im[j];
            re[2 * j]     = r0 * cw[w];
            im[2 * j]     = i0 * cw[w];
            re[2 * j + 1] = i0 * sw[w];
            im[2 * j + 1] = -r0 * sw[w];
        }
    }
    #pragma unroll
    for (int l = 0; l < 2; ++l) {
        // ring of CRZ(phi, wires=[i, (i+1)%4]) — diagonal
        #pragma unroll
        for (int i = 0; i < 4; ++i) {
            const float cc = s_trig[l * 8 + i];
            const float ss = s_trig[16 + l * 8 + i];
            #pragma unroll
            for (int k = 0; k < 16; ++k) {
                const int cb = (k >> (3 - i)) & 1;
                const int tb = (k >> (3 - ((i + 1) & 3))) & 1;
                if (cb) {
                    const float pr = cc, pi = tb ? ss : -ss;
                    const float r = re[k], mm = im[k];
                    re[k] = r * pr - mm * pi;
                    im[k] = r * pi + mm * pr;
                }
            }
        }
        // RY on each wire i: bit (3-i), stride 8>>i
        #pragma unroll
        for (int i = 0; i < 4; ++i) {
            const float ct = s_trig[l * 8 + 4 + i];
            const float st = s_trig[16 + l * 8 + 4 + i];
            const int str = 8 >> i;
            #pragma unroll
            for (int k = 0; k < 16; ++k) {
                if ((k & str) == 0) {
                    const int k1 = k + str;
                    const float r0 = re[k], r1 = re[k1];
                    const float i0 = im[k], i1 = im[k1];
                    re[k]  = ct * r0 - st * r1;
                    re[k1] = st * r0 + ct * r1;
                    im[k]  = ct * i0 - st * i1;
                    im[k1] = st * i0 + ct * i1;
                }
            }
        }
    }
    float q0 = 0.f, q1 = 0.f, q2 = 0.f, q3 = 0.f;
    #pragma unroll
    for (int k = 0; k < 16; ++k) {
        const float p = re[k] * re[k] + im[k] * im[k];
        q0 += (k & 8) ? -p : p;
        q1 += (k & 4) ? -p : p;
        q2 += (k & 2) ? -p : p;
        q3 += (k & 1) ? -p : p;
    }
    qout[0] = q0; qout[1] = q1; qout[2] = q2; qout[3] = q3;
}

// ============================ PHASE A =======================================
// qout[n][0..3] = circuit( x[n,:] @ Wq^T + bq )
template<bool BF16>
__device__ __forceinline__ void bodyA(
    const void* __restrict__ x,
    const void* __restrict__ qwp,
    const void* __restrict__ Wq,
    const void* __restrict__ bq,
    float* __restrict__ qout,
    v4f* s_wq4, float* s_trig)
{
    const int tid = threadIdx.x;
    float* s_wqf = (float*)s_wq4;
    for (int i = tid; i < 4 * EDIM; i += NTHREADS) s_wqf[i] = ld1<BF16>(Wq, i);
    if (tid < 16) {
        const float wv = ld1<BF16>(qwp, tid);
        s_trig[tid]      = cosf(0.5f * wv);
        s_trig[16 + tid] = sinf(0.5f * wv);
    }
    __syncthreads();

    const int t = tid >> 3;               // token within block
    const int s = tid & 7;                // e-slice lane
    const int n = blockIdx.x * TPB_A + t;

    float acc0 = 0.f, acc1 = 0.f, acc2 = 0.f, acc3 = 0.f;
    #pragma unroll
    for (int m = 0; m < 16; ++m) {
        const int e4 = s + 8 * m;
        float xf0, xf1, xf2, xf3;
        if constexpr (BF16) {
            const v4h xv = ((const v4h*)x)[(size_t)n * 128 + e4];
            xf0 = bf2f(xv.x); xf1 = bf2f(xv.y); xf2 = bf2f(xv.z); xf3 = bf2f(xv.w);
        } else {
            const v4f xv = ((const v4f*)x)[(size_t)n * 128 + e4];
            xf0 = xv.x; xf1 = xv.y; xf2 = xv.z; xf3 = xv.w;
        }
        const v4f w0 = s_wq4[0 * 128 + e4];
        const v4f w1 = s_wq4[1 * 128 + e4];
        const v4f w2 = s_wq4[2 * 128 + e4];
        const v4f w3 = s_wq4[3 * 128 + e4];
        acc0 = fmaf(xf0, w0.x, acc0); acc0 = fmaf(xf1, w0.y, acc0);
        acc0 = fmaf(xf2, w0.z, acc0); acc0 = fmaf(xf3, w0.w, acc0);
        acc1 = fmaf(xf0, w1.x, acc1); acc1 = fmaf(xf1, w1.y, acc1);
        acc1 = fmaf(xf2, w1.z, acc1); acc1 = fmaf(xf3, w1.w, acc1);
        acc2 = fmaf(xf0, w2.x, acc2); acc2 = fmaf(xf1, w2.y, acc2);
        acc2 = fmaf(xf2, w2.z, acc2); acc2 = fmaf(xf3, w2.w, acc2);
        acc3 = fmaf(xf0, w3.x, acc3); acc3 = fmaf(xf1, w3.y, acc3);
        acc3 = fmaf(xf2, w3.z, acc3); acc3 = fmaf(xf3, w3.w, acc3);
    }

    float qin[4] = {acc0, acc1, acc2, acc3};
    #pragma unroll
    for (int q = 0; q < 4; ++q) {
        float v = qin[q];
        v += __shfl_xor(v, 1);
        v += __shfl_xor(v, 2);
        v += __shfl_xor(v, 4);
        qin[q] = v + ld1<BF16>(bq, q);
    }

    float qo[4];
    circuit4(qin, s_trig, qo);

    if (s == 0) {
        v4f qv; qv.x = qo[0]; qv.y = qo[1]; qv.z = qo[2]; qv.w = qo[3];
        ((v4f*)qout)[n] = qv;   // cached store: stays in L2/L3 for phase B
    }
}

__global__ __launch_bounds__(NTHREADS)
void qlayer_A(const void* __restrict__ x,
              const void* __restrict__ qw,
              const void* __restrict__ Wq,
              const void* __restrict__ bq,
              float* __restrict__ qout)
{
    __shared__ v4f  s_wq4[4 * 128];
    __shared__ float s_trig[32];
    __shared__ int  s_zc, s_vc;
    const bool isbf = detect_block((const u32*)x, threadIdx.x, &s_zc, &s_vc);
    if (isbf) bodyA<true >(x, qw, Wq, bq, qout, s_wq4, s_trig);
    else      bodyA<false>(x, qw, Wq, bq, qout, s_wq4, s_trig);
}

// ============================ PHASE B =======================================
// out[n][4e4..4e4+3] = qout[n][:] @ Wc[4e4+j][:] + bc ; pure write stream.
// Thread owns one e4 slot, Wc rows + bc live in registers, zero LDS.
template<bool BF16>
__device__ __forceinline__ void bodyB(
    const float* __restrict__ qout,
    const void* __restrict__ Wc,
    const void* __restrict__ bc,
    void* __restrict__ out)
{
    const int tid = threadIdx.x;
    const int e4  = tid & 127;
    const int h   = tid >> 7;

    v4f w[4];
    #pragma unroll
    for (int j = 0; j < 4; ++j) {
        if constexpr (BF16) {
            const v4h wv = ((const v4h*)Wc)[4 * e4 + j];
            w[j].x = bf2f(wv.x); w[j].y = bf2f(wv.y);
            w[j].z = bf2f(wv.z); w[j].w = bf2f(wv.w);
        } else {
            w[j] = ((const v4f*)Wc)[4 * e4 + j];
        }
    }
    v4f bcv;
    if constexpr (BF16) {
        const v4h bv = ((const v4h*)bc)[e4];
        bcv.x = bf2f(bv.x); bcv.y = bf2f(bv.y); bcv.z = bf2f(bv.z); bcv.w = bf2f(bv.w);
    } else {
        bcv = ((const v4f*)bc)[e4];
    }

    const int n0 = blockIdx.x * TPB_B;
    #pragma unroll
    for (int k = 0; k < 16; ++k) {
        const int n = n0 + 2 * k + h;
        const v4f qv = ((const v4f*)qout)[n];
        v4f o = bcv;
        o.x = fmaf(qv.x, w[0].x, o.x); o.x = fmaf(qv.y, w[0].y, o.x);
        o.x = fmaf(qv.z, w[0].z, o.x); o.x = fmaf(qv.w, w[0].w, o.x);
        o.y = fmaf(qv.x, w[1].x, o.y); o.y = fmaf(qv.y, w[1].y, o.y);
        o.y = fmaf(qv.z, w[1].z, o.y); o.y = fmaf(qv.w, w[1].w, o.y);
        o.z = fmaf(qv.x, w[2].x, o.z); o.z = fmaf(qv.y, w[2].y, o.z);
        o.z = fmaf(qv.z, w[2].z, o.z); o.z = fmaf(qv.w, w[2].w, o.z);
        o.w = fmaf(qv.x, w[3].x, o.w); o.w = fmaf(qv.y, w[3].y, o.w);
        o.w = fmaf(qv.z, w[3].z, o.w); o.w = fmaf(qv.w, w[3].w, o.w);
        if constexpr (BF16) {
            v4h ov;
            ov.x = (u16)f2bfbits(o.x);
            ov.y = (u16)f2bfbits(o.y);
            ov.z = (u16)f2bfbits(o.z);
            ov.w = (u16)f2bfbits(o.w);
            __builtin_nontemporal_store(ov, (v4h*)out + (size_t)n * 128 + e4);
        } else {
            __builtin_nontemporal_store(o, (v4f*)out + (size_t)n * 128 + e4);
        }
    }
}

__global__ __launch_bounds__(NTHREADS)
void qlayer_B(const float* __restrict__ qout,
              const void* __restrict__ x,     // only for dtype detection
              const void* __restrict__ Wc,
              const void* __restrict__ bc,
              void* __restrict__ out)
{
    __shared__ int s_zc, s_vc;
    const bool isbf = detect_block((const u32*)x, threadIdx.x, &s_zc, &s_vc);
    if (isbf) bodyB<true >(qout, Wc, bc, out);
    else      bodyB<false>(qout, Wc, bc, out);
}

// ============== FUSED FALLBACK (verified Round-2 kernel) ====================
template<bool BF16>
__device__ __forceinline__ void bodyF(
    const void* __restrict__ x,
    const void* __restrict__ qwp,
    const void* __restrict__ Wq,
    const void* __restrict__ bq,
    const void* __restrict__ Wc,
    const void* __restrict__ bc,
    void* __restrict__ out,
    v4f* s_wq4, v4f* s_wcc4, v4f* s_bc4, float* s_trig)
{
    const int tid = threadIdx.x;
    float* s_wqf  = (float*)s_wq4;
    float* s_wccf = (float*)s_wcc4;
    float* s_bcf  = (float*)s_bc4;

    for (int i = tid; i < 4 * EDIM; i += NTHREADS) s_wqf[i] = ld1<BF16>(Wq, i);
    for (int i = tid; i < 4 * EDIM; i += NTHREADS) {
        const int e4 = (i >> 2) & 127, k = i & 3, q = i >> 9;
        s_wccf[i] = ld1<BF16>(Wc, e4 * 16 + k * 4 + q);
    }
    for (int i = tid; i < EDIM; i += NTHREADS) s_bcf[i] = ld1<BF16>(bc, i);
    if (tid < 16) {
        const float wv = ld1<BF16>(qwp, tid);
        s_trig[tid]      = cosf(0.5f * wv);
        s_trig[16 + tid] = sinf(0.5f * wv);
    }
    __syncthreads();

    const int t = tid >> 3;
    const int s = tid & 7;
    const int n = blockIdx.x * 32 + t;

    float acc0 = 0.f, acc1 = 0.f, acc2 = 0.f, acc3 = 0.f;
    #pragma unroll
    for (int m = 0; m < 16; ++m) {
        const int e4 = s + 8 * m;
        float xf0, xf1, xf2, xf3;
        if constexpr (BF16) {
            const v4h xv = ((const v4h*)x)[(size_t)n * 128 + e4];
            xf0 = bf2f(xv.x); xf1 = bf2f(xv.y); xf2 = bf2f(xv.z); xf3 = bf2f(xv.w);
        } else {
            const v4f xv = ((const v4f*)x)[(size_t)n * 128 + e4];
            xf0 = xv.x; xf1 = xv.y; xf2 = xv.z; xf3 = xv.w;
        }
        const v4f w0 = s_wq4[0 * 128 + e4];
        const v4f w1 = s_wq4[1 * 128 + e4];
        const v4f w2 = s_wq4[2 * 128 + e4];
        const v4f w3 = s_wq4[3 * 128 + e4];
        acc0 = fmaf(xf0, w0.x, acc0); acc0 = fmaf(xf1, w0.y, acc0);
        acc0 = fmaf(xf2, w0.z, acc0); acc0 = fmaf(xf3, w0.w, acc0);
        acc1 = fmaf(xf0, w1.x, acc1); acc1 = fmaf(xf1, w1.y, acc1);
        acc1 = fmaf(xf2, w1.z, acc1); acc1 = fmaf(xf3, w1.w, acc1);
        acc2 = fmaf(xf0, w2.x, acc2); acc2 = fmaf(xf1, w2.y, acc2);
        acc2 = fmaf(xf2, w2.z, acc2); acc2 = fmaf(xf3, w2.w, acc2);
        acc3 = fmaf(xf0, w3.x, acc3); acc3 = fmaf(xf1, w3.y, acc3);
        acc3 = fmaf(xf2, w3.z, acc3); acc3 = fmaf(xf3, w3.w, acc3);
    }

    float qin[4] = {acc0, acc1, acc2, acc3};
    #pragma unroll
    for (int q = 0; q < 4; ++q) {
        float v = qin[q];
        v += __shfl_xor(v, 1);
        v += __shfl_xor(v, 2);
        v += __shfl_xor(v, 4);
        qin[q] = v + ld1<BF16>(bq, q);
    }

    float qo[4];
    circuit4(qin, s_trig, qo);

    #pragma unroll
    for (int m = 0; m < 16; ++m) {
        const int e4 = s + 8 * m;
        v4f o = s_bc4[e4];
        #pragma unroll
        for (int q = 0; q < 4; ++q) {
            const v4f wv = s_wcc4[q * 128 + e4];
            o.x = fmaf(qo[q], wv.x, o.x);
            o.y = fmaf(qo[q], wv.y, o.y);
            o.z = fmaf(qo[q], wv.z, o.z);
            o.w = fmaf(qo[q], wv.w, o.w);
        }
        if constexpr (BF16) {
            v4h ov;
            ov.x = (u16)f2bfbits(o.x);
            ov.y = (u16)f2bfbits(o.y);
            ov.z = (u16)f2bfbits(o.z);
            ov.w = (u16)f2bfbits(o.w);
            __builtin_nontemporal_store(ov, (v4h*)out + (size_t)n * 128 + e4);
        } else {
            __builtin_nontemporal_store(o, (v4f*)out + (size_t)n * 128 + e4);
        }
    }
}

__global__ __launch_bounds__(NTHREADS, 4)
void qlayer_fused(const void* __restrict__ x,
                  const void* __restrict__ qw,
                  const void* __restrict__ Wq,
                  const void* __restrict__ bq,
                  const void* __restrict__ Wc,
                  const void* __restrict__ bc,
                  void* __restrict__ out)
{
    __shared__ v4f  s_wq4[4 * 128];
    __shared__ v4f  s_wcc4[4 * 128];
    __shared__ v4f  s_bc4[128];
    __shared__ float s_trig[32];
    __shared__ int  s_zc, s_vc;
    const bool isbf = detect_block((const u32*)x, threadIdx.x, &s_zc, &s_vc);
    if (isbf) bodyF<true >(x, qw, Wq, bq, Wc, bc, out, s_wq4, s_wcc4, s_bc4, s_trig);
    else      bodyF<false>(x, qw, Wq, bq, Wc, bc, out, s_wq4, s_wcc4, s_bc4, s_trig);
}

extern "C" void kernel_launch(void* const* d_in, const int* in_sizes, int n_in,
                              void* d_out, int out_size, void* d_ws, size_t ws_size,
                              hipStream_t stream)
{
    const void* x  = d_in[0];
    const void* qw = d_in[1];
    const void* Wq = d_in[2];
    const void* bq = d_in[3];
    const void* Wc = d_in[4];
    const void* bc = d_in[5];
    (void)in_sizes; (void)n_in; (void)out_size;

    const size_t QOUT_BYTES = (size_t)NTOK * 4 * sizeof(float);  // 1 MiB
    if (ws_size >= QOUT_BYTES && d_ws != nullptr) {
        float* qout = (float*)d_ws;
        qlayer_A<<<NBLK_A, NTHREADS, 0, stream>>>(x, qw, Wq, bq, qout);
        qlayer_B<<<NBLK_B, NTHREADS, 0, stream>>>(qout, x, Wc, bc, d_out);
    } else {
        qlayer_fused<<<NTOK / 32, NTHREADS, 0, stream>>>(x, qw, Wq, bq, Wc, bc, d_out);
    }
}

// Round 5
// 246.595 us; speedup vs baseline: 1.0441x; 1.0441x over previous
//
#include <hip/hip_runtime.h>

#define EDIM     512
#define NTOK     (512 * 128)   // B*S = 65536
#define NTHREADS 256
#define TPB      32            // tokens per block (8 lanes per token)
#define NBLOCKS  (NTOK / TPB)  // 2048 blocks -> 8 blocks/CU

typedef unsigned short u16;
typedef unsigned int   u32;
typedef float v4f __attribute__((ext_vector_type(4)));
typedef u16   v4h __attribute__((ext_vector_type(4)));

__device__ __forceinline__ float bf2f(u16 u) { return __uint_as_float(((u32)u) << 16); }

__device__ __forceinline__ u32 f2bfbits(float f) {
    // round-to-nearest-even f32 -> bf16
    u32 b = __float_as_uint(f);
    return (b + 0x7fffu + ((b >> 16) & 1u)) >> 16;
}

// ---- inline HW trig: v_sin_f32/v_cos_f32, branchless, no libcall/scratch ---
__device__ __forceinline__ float fsin(float a) { return __sinf(a); }
__device__ __forceinline__ float fcos(float a) { return __cosf(a); }

// ---- dtype-generic scalar load ---------------------------------------------
template<bool BF16>
__device__ __forceinline__ float ld1(const void* p, int off) {
    if constexpr (BF16) return bf2f(((const u16*)p)[off]);
    else                return ((const float*)p)[off];
}

// ---- per-block pipeline: 32 tokens, 8 lanes/token --------------------------
template<bool BF16>
__device__ __forceinline__ void body(
    const void* __restrict__ x,
    const void* __restrict__ qwp,  // [2][8]
    const void* __restrict__ Wq,   // [4][512]
    const void* __restrict__ bq,   // [4]
    const void* __restrict__ Wc,   // [512][4]
    const void* __restrict__ bc,   // [512]
    void* __restrict__ out,
    v4f* s_wq4,                    // [4][128]  (= Wq rows as float4)
    v4f* s_wcc4,                   // [4][128]  (col-major: {Wc[4e4+k][q]}k)
    v4f* s_bc4,                    // [128]
    float* s_trig)                 // [32] cos/sin of 0.5*qw
{
    const int tid = threadIdx.x;
    float* s_wqf  = (float*)s_wq4;
    float* s_wccf = (float*)s_wcc4;
    float* s_bcf  = (float*)s_bc4;

    // cooperative LDS staging of the (tiny) weights, converted to f32
    for (int i = tid; i < 4 * EDIM; i += NTHREADS) s_wqf[i] = ld1<BF16>(Wq, i);
    for (int i = tid; i < 4 * EDIM; i += NTHREADS) {
        const int e4 = (i >> 2) & 127, k = i & 3, q = i >> 9;
        s_wccf[i] = ld1<BF16>(Wc, e4 * 16 + k * 4 + q);   // Wc[4*e4+k][q]
    }
    for (int i = tid; i < EDIM; i += NTHREADS) s_bcf[i] = ld1<BF16>(bc, i);
    if (tid < 16) {
        const float wv = ld1<BF16>(qwp, tid);
        s_trig[tid]      = fcos(0.5f * wv);
        s_trig[16 + tid] = fsin(0.5f * wv);
    }
    __syncthreads();

    const int t = tid >> 3;               // token within block
    const int s = tid & 7;                // e-slice lane
    const int n = blockIdx.x * TPB + t;   // global token (grid exact, no bounds check)

    // ---- stage 1: q_in = x[n,:] @ Wq^T + bq, 8 lanes/token, coalesced ----
    float acc0 = 0.f, acc1 = 0.f, acc2 = 0.f, acc3 = 0.f;
    #pragma unroll
    for (int m = 0; m < 16; ++m) {
        const int e4 = s + 8 * m;
        float xf0, xf1, xf2, xf3;
        if constexpr (BF16) {
            const v4h xv = ((const v4h*)x)[(size_t)n * 128 + e4];
            xf0 = bf2f(xv.x); xf1 = bf2f(xv.y); xf2 = bf2f(xv.z); xf3 = bf2f(xv.w);
        } else {
            const v4f xv = ((const v4f*)x)[(size_t)n * 128 + e4];
            xf0 = xv.x; xf1 = xv.y; xf2 = xv.z; xf3 = xv.w;
        }
        const v4f w0 = s_wq4[0 * 128 + e4];
        const v4f w1 = s_wq4[1 * 128 + e4];
        const v4f w2 = s_wq4[2 * 128 + e4];
        const v4f w3 = s_wq4[3 * 128 + e4];
        acc0 = fmaf(xf0, w0.x, acc0); acc0 = fmaf(xf1, w0.y, acc0);
        acc0 = fmaf(xf2, w0.z, acc0); acc0 = fmaf(xf3, w0.w, acc0);
        acc1 = fmaf(xf0, w1.x, acc1); acc1 = fmaf(xf1, w1.y, acc1);
        acc1 = fmaf(xf2, w1.z, acc1); acc1 = fmaf(xf3, w1.w, acc1);
        acc2 = fmaf(xf0, w2.x, acc2); acc2 = fmaf(xf1, w2.y, acc2);
        acc2 = fmaf(xf2, w2.z, acc2); acc2 = fmaf(xf3, w2.w, acc2);
        acc3 = fmaf(xf0, w3.x, acc3); acc3 = fmaf(xf1, w3.y, acc3);
        acc3 = fmaf(xf2, w3.z, acc3); acc3 = fmaf(xf3, w3.w, acc3);
    }
    // butterfly reduce across the token's 8 lanes (wave-contiguous)
    float qin[4] = {acc0, acc1, acc2, acc3};
    #pragma unroll
    for (int q = 0; q < 4; ++q) {
        float v = qin[q];
        v += __shfl_xor(v, 1);
        v += __shfl_xor(v, 2);
        v += __shfl_xor(v, 4);
        qin[q] = v + ld1<BF16>(bq, q);   // all 8 lanes hold the full dot
    }

    // ---- stage 2: literal 4-qubit circuit (redundant x8, no divergence) ----
    float cw[4], sw[4];
    #pragma unroll
    for (int w = 0; w < 4; ++w) {
        const float h = 0.5f * qin[w];
        cw[w] = fcos(h);
        sw[w] = fsin(h);
    }

    float re[16], im[16];
    re[0] = 1.f; im[0] = 0.f;
    #pragma unroll
    for (int w = 0; w < 4; ++w) {
        #pragma unroll
        for (int j = (1 << w) - 1; j >= 0; --j) {
            const float r0 = re[j], i0 = im[j];
            re[2 * j]     = r0 * cw[w];
            im[2 * j]     = i0 * cw[w];
            re[2 * j + 1] = i0 * sw[w];
            im[2 * j + 1] = -r0 * sw[w];
        }
    }
    #pragma unroll
    for (int l = 0; l < 2; ++l) {
        // ring of CRZ(phi, wires=[i, (i+1)%4]) — diagonal
        #pragma unroll
        for (int i = 0; i < 4; ++i) {
            const float cc = s_trig[l * 8 + i];
            const float ss = s_trig[16 + l * 8 + i];
            #pragma unroll
            for (int k = 0; k < 16; ++k) {
                const int cb = (k >> (3 - i)) & 1;
                const int tb = (k >> (3 - ((i + 1) & 3))) & 1;
                if (cb) {
                    const float pr = cc, pi = tb ? ss : -ss;  // e^{i*0.5*phi*(2tb-1)}
                    const float r = re[k], m = im[k];
                    re[k] = r * pr - m * pi;
                    im[k] = r * pi + m * pr;
                }
            }
        }
        // RY on each wire i: bit (3-i), stride 8>>i
        #pragma unroll
        for (int i = 0; i < 4; ++i) {
            const float ct = s_trig[l * 8 + 4 + i];
            const float st = s_trig[16 + l * 8 + 4 + i];
            const int str = 8 >> i;
            #pragma unroll
            for (int k = 0; k < 16; ++k) {
                if ((k & str) == 0) {
                    const int k1 = k + str;
                    const float r0 = re[k], r1 = re[k1];
                    const float i0 = im[k], i1 = im[k1];
                    re[k]  = ct * r0 - st * r1;
                    re[k1] = st * r0 + ct * r1;
                    im[k]  = ct * i0 - st * i1;
                    im[k1] = st * i0 + ct * i1;
                }
            }
        }
    }
    float qout[4] = {0.f, 0.f, 0.f, 0.f};
    #pragma unroll
    for (int k = 0; k < 16; ++k) {
        const float p = re[k] * re[k] + im[k] * im[k];
        qout[0] += (k & 8) ? -p : p;
        qout[1] += (k & 4) ? -p : p;
        qout[2] += (k & 2) ? -p : p;
        qout[3] += (k & 1) ? -p : p;
    }

    // ---- stage 3: out[n,:] = q_out @ Wc^T + bc, coalesced float4 NT stores ----
    #pragma unroll
    for (int m = 0; m < 16; ++m) {
        const int e4 = s + 8 * m;
        v4f o = s_bc4[e4];
        #pragma unroll
        for (int q = 0; q < 4; ++q) {
            const v4f wv = s_wcc4[q * 128 + e4];
            o.x = fmaf(qout[q], wv.x, o.x);
            o.y = fmaf(qout[q], wv.y, o.y);
            o.z = fmaf(qout[q], wv.z, o.z);
            o.w = fmaf(qout[q], wv.w, o.w);
        }
        if constexpr (BF16) {
            v4h ov;
            ov.x = (u16)f2bfbits(o.x);
            ov.y = (u16)f2bfbits(o.y);
            ov.z = (u16)f2bfbits(o.z);
            ov.w = (u16)f2bfbits(o.w);
            __builtin_nontemporal_store(ov, (v4h*)out + (size_t)n * 128 + e4);
        } else {
            __builtin_nontemporal_store(o, (v4f*)out + (size_t)n * 128 + e4);
        }
    }
}

__global__ __launch_bounds__(NTHREADS, 4)
void qlayer_kernel(const void* __restrict__ x,
                   const void* __restrict__ qw,
                   const void* __restrict__ Wq,
                   const void* __restrict__ bq,
                   const void* __restrict__ Wc,
                   const void* __restrict__ bc,
                   void* __restrict__ out)
{
    __shared__ v4f  s_wq4[4 * 128];
    __shared__ v4f  s_wcc4[4 * 128];
    __shared__ v4f  s_bc4[128];
    __shared__ float s_trig[32];
    __shared__ int  s_zc, s_vc;

    const int tid = threadIdx.x;

    // ---- folded 3-way container detection (each block, redundantly) ----
    // true bf16 container : low u16 of word is valid N(0,1)-scale bf16 -> v~512
    // true f32 container  : low u16 random mantissa -> v~19%, z~0
    // f32 holding bf16-rounded values: low u16 == 0 -> z~512
    if (tid == 0) { s_zc = 0; s_vc = 0; }
    __syncthreads();
    {
        int z = 0, v = 0;
        #pragma unroll
        for (int i = 0; i < 2; ++i) {
            const u32 w = ((const u32*)x)[tid + 256 * i];
            if ((w & 0xFFFFu) == 0u) z++;
            const u32 e = (w >> 7) & 0xFFu;
            if (e != 0u && e >= 96u && e <= 143u) v++;
        }
        if (z) atomicAdd(&s_zc, z);
        if (v) atomicAdd(&s_vc, v);
    }
    __syncthreads();
    const bool isbf = (s_zc < 384 && s_vc >= 384);   // uniform across block

    if (isbf)
        body<true >(x, qw, Wq, bq, Wc, bc, out, s_wq4, s_wcc4, s_bc4, s_trig);
    else
        body<false>(x, qw, Wq, bq, Wc, bc, out, s_wq4, s_wcc4, s_bc4, s_trig);
}

extern "C" void kernel_launch(void* const* d_in, const int* in_sizes, int n_in,
                              void* d_out, int out_size, void* d_ws, size_t ws_size,
                              hipStream_t stream)
{
    const void* x  = d_in[0];
    const void* qw = d_in[1];
    const void* Wq = d_in[2];
    const void* bq = d_in[3];
    const void* Wc = d_in[4];
    const void* bc = d_in[5];
    (void)in_sizes; (void)n_in; (void)out_size; (void)d_ws; (void)ws_size;

    qlayer_kernel<<<NBLOCKS, NTHREADS, 0, stream>>>(x, qw, Wq, bq, Wc, bc, d_out);
}